// Round 12
// baseline (61.336 us; speedup 1.0000x reference)
//
#include <hip/hip_runtime.h>
#include <math.h>

// Problem constants (from reference)
#define M_SLOTS 64
#define E_DIM   64
#define KEY_DIM 64
#define V_DIM   128
#define K_CAT   4
#define S_LEN   200

typedef __attribute__((ext_vector_type(8)))  short short8;
typedef __attribute__((ext_vector_type(16))) float f32x16;

// ---------------- ws layout (float offsets) ----------------
// wsum_p [S][4][64] + emsum_p [S][4] — fully rewritten by K1 each call (no zeroing).
#define OFF_WSUMP  0
#define OFF_EMSUMP (S_LEN * 4 * M_SLOTS)

// pack two f32 -> bf16 pair, round-to-nearest-even (MFMA inputs)
__device__ __forceinline__ unsigned pk2rne(float lo, float hi) {
    unsigned ul = __float_as_uint(lo); ul += 0x7fffu + ((ul >> 16) & 1u);
    unsigned uh = __float_as_uint(hi); uh += 0x7fffu + ((uh >> 16) & 1u);
    return __builtin_amdgcn_perm(uh, ul, 0x07060302u);
}
__device__ __forceinline__ unsigned short bf16rne(float f) {
    unsigned u = __float_as_uint(f);
    return (unsigned short)((u + 0x7fffu + ((u >> 16) & 1u)) >> 16);
}
__device__ __forceinline__ short8 as_s8(uint4 u) { return __builtin_bit_cast(short8, u); }

__device__ __forceinline__ void gpcm_store(float th, int q,
                                           const float* __restrict__ alpha_mean,
                                           const float* __restrict__ beta_base,
                                           const float* __restrict__ beta_gaps,
                                           float* __restrict__ out, size_t idx) {
    float a  = __expf(alpha_mean[q]);
    float b0 = beta_base[q];
    float2 g = *reinterpret_cast<const float2*>(&beta_gaps[q * (K_CAT - 2)]);
    float g0 = log1pf(__expf(g.x));
    float g1 = log1pf(__expf(g.y));
    float be1 = b0 + g0;
    float be2 = be1 + g1;
    float z0 = a * (th - b0);
    float z1 = a * (th - be1);
    float z2 = a * (th - be2);
    float c1 = z0, c2 = z0 + z1, c3 = z0 + z1 + z2;
    float cm = fmaxf(fmaxf(0.f, c1), fmaxf(c2, c3));
    float e0 = __expf(0.f - cm), e1 = __expf(c1 - cm), e2 = __expf(c2 - cm), e3 = __expf(c3 - cm);
    float si = __fdividef(1.0f, e0 + e1 + e2 + e3);
    float4 o4 = make_float4(e0 * si, e1 * si, e2 * si, e3 * si);
    *reinterpret_cast<float4*>(&out[idx * K_CAT]) = o4;
}

// In-block Ct build: wave wv computes 32x32 tile (m0=(wv&1)*32, e0=(wv>>1)*32) of
// Ct[m][e] = sum_k mkeys[m][k]*q2k_w[e][k] via 4 MFMAs, writes bf16 into
// XOR-swizzled LDS (row stride 128B would be a 32-way bank conflict otherwise).
__device__ __forceinline__ void ct_build(const float* __restrict__ q2k_w,
                                         const float* __restrict__ mkeys,
                                         unsigned short* ctL, int wv, int h, int p) {
    const int m0 = (wv & 1) * 32, e0 = (wv >> 1) * 32;
    f32x16 d;
    #pragma unroll
    for (int i = 0; i < 16; ++i) d[i] = 0.f;
    #pragma unroll
    for (int s = 0; s < 4; ++s) {
        const float* ar = mkeys + (m0 + p) * KEY_DIM + s * 16 + h * 8;
        const float* br = q2k_w + (e0 + p) * KEY_DIM + s * 16 + h * 8;
        float4 a0 = *(const float4*)ar, a1 = *(const float4*)(ar + 4);
        float4 b0 = *(const float4*)br, b1 = *(const float4*)(br + 4);
        uint4 au, bu;
        au.x = pk2rne(a0.x, a0.y); au.y = pk2rne(a0.z, a0.w);
        au.z = pk2rne(a1.x, a1.y); au.w = pk2rne(a1.z, a1.w);
        bu.x = pk2rne(b0.x, b0.y); bu.y = pk2rne(b0.z, b0.w);
        bu.z = pk2rne(b1.x, b1.y); bu.w = pk2rne(b1.z, b1.w);
        d = __builtin_amdgcn_mfma_f32_32x32x16_bf16(as_s8(au), as_s8(bu), d, 0, 0, 0);
    }
    #pragma unroll
    for (int j = 0; j < 16; ++j) {
        int row = (j & 3) + 8 * ((j >> 2) & 3) + 4 * h;
        int m = m0 + row, e = e0 + p;
        int off = m * 128 + (((e * 2)) ^ ((m & 7) << 4));
        *(unsigned short*)((char*)ctL + off) = bf16rne(d[j]);
    }
}

// Logits from LDS Ct: acc[mt][j] = bm + (Ct q)[m], m = (j&3)+8*((j>>2)&3)+4h+32mt.
__device__ __forceinline__ void mfma_logits_lds(
    const float4 qf[8], const unsigned short* ctL, const float* bmL,
    int h, int p, f32x16 acc[2])
{
    #pragma unroll
    for (int mt = 0; mt < 2; ++mt)
        #pragma unroll
        for (int g = 0; g < 4; ++g) {
            float4 v = *(const float4*)(bmL + 8 * g + 4 * h + 32 * mt);
            acc[mt][4 * g + 0] = v.x; acc[mt][4 * g + 1] = v.y;
            acc[mt][4 * g + 2] = v.z; acc[mt][4 * g + 3] = v.w;
        }
    const int sw = (p & 7) << 4;   // (p&7) == ((p+32)&7)
    #pragma unroll
    for (int s = 0; s < 4; ++s) {
        uint4 bf;
        bf.x = pk2rne(qf[2 * s].x,     qf[2 * s].y);
        bf.y = pk2rne(qf[2 * s].z,     qf[2 * s].w);
        bf.z = pk2rne(qf[2 * s + 1].x, qf[2 * s + 1].y);
        bf.w = pk2rne(qf[2 * s + 1].z, qf[2 * s + 1].w);
        short8 bfr = as_s8(bf);
        const int ebyte = (s * 32 + h * 16) ^ sw;
        uint4 a0 = *(const uint4*)((const char*)ctL + p * 128 + ebyte);
        uint4 a1 = *(const uint4*)((const char*)ctL + (p + 32) * 128 + ebyte);
        acc[0] = __builtin_amdgcn_mfma_f32_32x32x16_bf16(as_s8(a0), bfr, acc[0], 0, 0, 0);
        acc[1] = __builtin_amdgcn_mfma_f32_32x32x16_bf16(as_s8(a1), bfr, acc[1], 0, 0, 0);
    }
}

// K1: stats. Grid (S, B/128), 256 threads. Per-block Ct/bm/lsEv rebuild (hidden
// under q gather), MFMA logits, softmax, pair-fold, block-fold -> plain stores.
__global__ __launch_bounds__(256, 3) void k_attn(
    const float* __restrict__ qtab, const int* __restrict__ qs, const int* __restrict__ rs,
    const float* __restrict__ q2k_w, const float* __restrict__ q2k_b,
    const float* __restrict__ mkeys,
    const float* __restrict__ qa_w, const float* __restrict__ qa_b,
    const float* __restrict__ ev_w, const float* __restrict__ ev_b,
    float* __restrict__ wsum_p, float* __restrict__ emsum_p,
    int B, float invNQ)
{
    __shared__ unsigned short ctL[M_SLOTS * E_DIM];
    __shared__ float bmL[M_SLOTS];
    __shared__ float4 lsEv[E_DIM];
    __shared__ float lsBB;
    __shared__ float lsFold[4][M_SLOTS];
    __shared__ float lsEvw[4];
    const int tid = threadIdx.x, wv = tid >> 6, lane = tid & 63;
    const int h = lane >> 5, p = lane & 31;
    const int t = blockIdx.x, by = blockIdx.y;
    const int b = by * 128 + wv * 32 + p;

    // dependent gather chain first
    const int q = qs[(size_t)b * S_LEN + t];
    const int r = rs[(size_t)b * S_LEN + t];
    const float* qrow = qtab + (size_t)q * E_DIM;
    float4 qf[8];
    #pragma unroll
    for (int s = 0; s < 4; ++s) {
        const float4* src = (const float4*)(qrow + s * 16 + h * 8);
        qf[2 * s] = src[0]; qf[2 * s + 1] = src[1];
    }

    // in-block preprocessing (overlaps gather latency)
    ct_build(q2k_w, mkeys, ctL, wv, h, p);
    if (wv == 1) {   // bm[m] = q2k_b . mkeys[m]; bbar
        float s = 0.f;
        const float4* mk = (const float4*)(mkeys + lane * KEY_DIM);
        const float4* qb = (const float4*)q2k_b;
        #pragma unroll
        for (int i = 0; i < KEY_DIM / 4; ++i) {
            float4 a = mk[i], c = qb[i];
            s += a.x * c.x + a.y * c.y + a.z * c.z + a.w * c.w;
        }
        bmL[lane] = s;
        float bbv = ev_b[lane] + ev_b[64 + lane];
        #pragma unroll
        for (int o = 32; o; o >>= 1) bbv += __shfl_xor(bbv, o);
        if (!lane) lsBB = bbv * (1.0f / V_DIM);
    }
    if (wv == 0) {   // lsEv[e] = (qa_w0, qa_w1, qa_b, rowmean ev_w[e])
        float wb = 0.f;
        const float4* er = (const float4*)(ev_w + (size_t)lane * V_DIM);
        #pragma unroll
        for (int i = 0; i < V_DIM / 4; ++i) {
            float4 v = er[i];
            wb += (v.x + v.y) + (v.z + v.w);
        }
        lsEv[lane] = make_float4(qa_w[lane], qa_w[E_DIM + lane], qa_b[lane],
                                 wb * (1.0f / V_DIM));
    }
    __syncthreads();

    f32x16 acc[2];
    mfma_logits_lds(qf, ctL, bmL, h, p, acc);

    // softmax over 64 slots of pair p (half h holds 32)
    float av[32];
    float ssum = 0.f;
    #pragma unroll
    for (int j = 0; j < 16; ++j) { av[j]      = __expf(acc[0][j]); ssum += av[j]; }
    #pragma unroll
    for (int j = 0; j < 16; ++j) { av[16 + j] = __expf(acc[1][j]); ssum += av[16 + j]; }
    ssum += __shfl_xor(ssum, 32);
    const float inv = __fdividef(1.0f, ssum);

    // fold normalized attn over 32 pairs; lane ends with slot jj=lane&31
    #pragma unroll
    for (int j = 0; j < 32; ++j) av[j] *= inv;
    #pragma unroll
    for (int step = 0; step < 5; ++step) {
        const int sh = 1 << step;
        #pragma unroll
        for (int j = 0; j < (32 >> step) / 2; ++j) {
            float p0 = av[2 * j]     + __shfl_xor(av[2 * j], sh);
            float p1 = av[2 * j + 1] + __shfl_xor(av[2 * j + 1], sh);
            av[j] = (lane & sh) ? p1 : p0;
        }
    }
    {
        const int jj = lane & 31;
        const int m = (jj & 3) + 8 * ((jj >> 2) & 3) + 4 * h + 32 * (jj >> 4);
        lsFold[wv][m] = av[0];
    }

    // evidence scalar per pair, folded over pairs
    float qn = (float)q * invNQ;
    float rn = (float)r * (1.0f / (K_CAT - 1));
    float evm = 0.f;
    #pragma unroll 8
    for (int e = 0; e < 32; ++e) {
        float4 pv = lsEv[h * 32 + e];
        float qa = fmaf(qn, pv.x, fmaf(rn, pv.y, pv.z));
        float ez = __expf(2.0f * qa);
        evm = fmaf(__fdividef(ez - 1.0f, ez + 1.0f), pv.w, evm);
    }
    evm += __shfl_xor(evm, 32);
    evm += lsBB;
    #pragma unroll
    for (int o = 16; o; o >>= 1) evm += __shfl_xor(evm, o);
    if (!lane) lsEvw[wv] = evm;
    __syncthreads();

    if (wv == 0) {
        float s4 = lsFold[0][lane] + lsFold[1][lane] + lsFold[2][lane] + lsFold[3][lane];
        wsum_p[(size_t)(t * 4 + by) * M_SLOTS + lane] = s4;
        if (!lane) emsum_p[t * 4 + by] = lsEvw[0] + lsEvw[1] + lsEvw[2] + lsEvw[3];
    }
}

// K2: output. Grid (S, B/128), 256 threads. In-block Ct/bm/rm0/p0 rebuild +
// 4-wave associative prefix over partials, MFMA recompute, theta dot, GPCM.
__global__ __launch_bounds__(256, 3) void k_out(
    const float* __restrict__ qtab, const int* __restrict__ qs,
    const float* __restrict__ q2k_w, const float* __restrict__ q2k_b,
    const float* __restrict__ mkeys,
    const float* __restrict__ means, const float* __restrict__ logvars,
    const float* __restrict__ wsum_p, const float* __restrict__ emsum_p,
    const float* __restrict__ alpha_mean, const float* __restrict__ beta_base,
    const float* __restrict__ beta_gaps, float* __restrict__ out,
    int B, float invB)
{
    __shared__ unsigned short ctL[M_SLOTS * E_DIM];
    __shared__ float bmL[M_SLOTS];
    __shared__ float lsW[4][M_SLOTS], lsN[4][M_SLOTS];
    __shared__ float lsRm0[M_SLOTS], lsP0[M_SLOTS];
    __shared__ float lsRmP[M_SLOTS];
    const int tid = threadIdx.x, wv = tid >> 6, lane = tid & 63;
    const int h = lane >> 5, p = lane & 31;
    const int t = blockIdx.x, by = blockIdx.y;
    const int b = by * 128 + wv * 32 + p;

    const int q = qs[(size_t)b * S_LEN + t];
    const float* qrow = qtab + (size_t)q * E_DIM;
    float4 qf[8];
    #pragma unroll
    for (int s = 0; s < 4; ++s) {
        const float4* src = (const float4*)(qrow + s * 16 + h * 8);
        qf[2 * s] = src[0]; qf[2 * s + 1] = src[1];
    }

    ct_build(q2k_w, mkeys, ctL, wv, h, p);
    if (wv == 1) {   // bm
        float s = 0.f;
        const float4* mk = (const float4*)(mkeys + lane * KEY_DIM);
        const float4* qb = (const float4*)q2k_b;
        #pragma unroll
        for (int i = 0; i < KEY_DIM / 4; ++i) {
            float4 a = mk[i], c = qb[i];
            s += a.x * c.x + a.y * c.y + a.z * c.z + a.w * c.w;
        }
        bmL[lane] = s;
    }
    if (wv == 2) {   // rm0/p0
        float s = 0.f;
        const float4* mr = (const float4*)(means + (size_t)lane * V_DIM);
        #pragma unroll
        for (int i = 0; i < V_DIM / 4; ++i) {
            float4 v = mr[i];
            s += (v.x + v.y) + (v.z + v.w);
        }
        lsRm0[lane] = s * (1.0f / V_DIM);
        lsP0[lane]  = __expf(-logvars[(size_t)lane * V_DIM]);  // row-uniform by construction
    }

    // associative prefix partials: wave wv sums t-segment [s0,s1) for m=lane
    {
        const int seg = (t + 3) >> 2;
        const int s0 = wv * seg, s1 = min(s0 + seg, t);
        float pw = 0.f, pn = 0.f;
        for (int s = s0; s < s1; ++s) {
            const float* wp = wsum_p + (size_t)s * 4 * M_SLOTS + lane;
            float w = wp[0] + wp[M_SLOTS] + wp[2 * M_SLOTS] + wp[3 * M_SLOTS];
            const float* ep = emsum_p + s * 4;
            float em = (ep[0] + ep[1]) + (ep[2] + ep[3]);
            pw += w;
            pn = fmaf(em, w, pn);
        }
        lsW[wv][lane] = pw; lsN[wv][lane] = pn;
    }
    __syncthreads();

    if (tid < 64) {
        const int m = tid;
        float sw = lsW[0][m] + lsW[1][m] + lsW[2][m] + lsW[3][m];
        float sn = lsN[0][m] + lsN[1][m] + lsN[2][m] + lsN[3][m];
        float den = lsP0[m] + sw * invB;
        float num = fmaf(lsP0[m], lsRm0[m], sn * (invB * invB));
        // MFMA slot-permuted index (r8-verified): idx = h(m)*32 + mt(m)*16 + j(m)
        const int idx = ((m >> 2) & 1) * 32 + ((m >> 5) & 1) * 16 + (m & 3) + 4 * ((m >> 3) & 3);
        lsRmP[idx] = num / den;   // state BEFORE update at t
    }
    __syncthreads();

    f32x16 acc[2];
    mfma_logits_lds(qf, ctL, bmL, h, p, acc);

    float ssum = 0.f, th = 0.f;
    const float* rmh = lsRmP + h * 32;
    #pragma unroll
    for (int j = 0; j < 16; ++j) {
        float e = __expf(acc[0][j]);
        ssum += e;
        th = fmaf(e, rmh[j], th);
    }
    #pragma unroll
    for (int j = 0; j < 16; ++j) {
        float e = __expf(acc[1][j]);
        ssum += e;
        th = fmaf(e, rmh[16 + j], th);
    }
    ssum += __shfl_xor(ssum, 32);
    th   += __shfl_xor(th, 32);
    th = __fdividef(th, ssum);

    if (!h) gpcm_store(th, q, alpha_mean, beta_base, beta_gaps, out, (size_t)b * S_LEN + t);
}

extern "C" void kernel_launch(void* const* d_in, const int* in_sizes, int n_in,
                              void* d_out, int out_size, void* d_ws, size_t ws_size,
                              hipStream_t stream) {
    const float* qtab       = (const float*)d_in[0];
    const float* alpha_mean = (const float*)d_in[1];
    const float* beta_base  = (const float*)d_in[2];
    const float* beta_gaps  = (const float*)d_in[3];
    const float* ab_means   = (const float*)d_in[4];
    const float* ab_logvars = (const float*)d_in[5];
    const float* mkeys      = (const float*)d_in[6];
    const float* q2k_w      = (const float*)d_in[7];
    const float* q2k_b      = (const float*)d_in[8];
    const float* qa_w       = (const float*)d_in[9];
    const float* qa_b       = (const float*)d_in[10];
    const float* ev_w       = (const float*)d_in[11];
    const float* ev_b       = (const float*)d_in[12];
    const int*   qs         = (const int*)d_in[13];
    const int*   rs         = (const int*)d_in[14];
    float* out = (float*)d_out;
    float* ws  = (float*)d_ws;

    const int NQ = in_sizes[1];
    const int S  = S_LEN;
    const int B  = in_sizes[13] / S;   // 512

    float* wsum_p  = ws + OFF_WSUMP;
    float* emsum_p = ws + OFF_EMSUMP;

    dim3 g(S, B / 128);
    k_attn<<<g, 256, 0, stream>>>(qtab, qs, rs, q2k_w, q2k_b, mkeys,
                                  qa_w, qa_b, ev_w, ev_b,
                                  wsum_p, emsum_p, B, 1.0f / (float)NQ);

    k_out<<<g, 256, 0, stream>>>(qtab, qs, q2k_w, q2k_b, mkeys,
                                 ab_means, ab_logvars, wsum_p, emsum_p,
                                 alpha_mean, beta_base, beta_gaps, out,
                                 B, 1.0f / (float)B);
}

// Round 13
// 47.221 us; speedup vs baseline: 1.2989x; 1.2989x over previous
//
#include <hip/hip_runtime.h>
#include <math.h>

// Problem constants (from reference)
#define M_SLOTS 64
#define E_DIM   64
#define KEY_DIM 64
#define V_DIM   128
#define K_CAT   4
#define S_LEN   200

typedef __attribute__((ext_vector_type(8)))  short short8;
typedef __attribute__((ext_vector_type(16))) float f32x16;

// ---------------- ws layout (float offsets) ----------------
#define OFF_CT     0                          // 4096 ushort = 2048 f  (Ct[m][e] bf16)
#define OFF_BM     2048                       // 64
#define OFF_WBAR   2112                       // 64
#define OFF_BBAR   2176                       // 1
#define OFF_RM0    2240                       // 64
#define OFF_P0     2304                       // 64
#define OFF_WSUM   2368                       // S*M = 12800 (zeroed by k_pre)
#define OFF_EMSUM  (OFF_WSUM + S_LEN*M_SLOTS) // 200 (zeroed, contiguous w/ wsum)

// work-item ranges for k_pre
#define PRE_CT_END   4096
#define PRE_BM_END   4160
#define PRE_WBAR_END 4224
#define PRE_BBAR     4224
#define PRE_RM_BEG   4225
#define PRE_RM_END   4289
#define PRE_Z_BEG    4289
#define PRE_Z_END    (4289 + S_LEN*M_SLOTS + S_LEN)

// pack two f32 -> bf16 pair, round-to-nearest-even (for MFMA inputs)
__device__ __forceinline__ unsigned pk2rne(float lo, float hi) {
    unsigned ul = __float_as_uint(lo); ul += 0x7fffu + ((ul >> 16) & 1u);
    unsigned uh = __float_as_uint(hi); uh += 0x7fffu + ((uh >> 16) & 1u);
    return __builtin_amdgcn_perm(uh, ul, 0x07060302u);
}
__device__ __forceinline__ unsigned short bf16rne(float f) {
    unsigned u = __float_as_uint(f);
    return (unsigned short)((u + 0x7fffu + ((u >> 16) & 1u)) >> 16);
}
__device__ __forceinline__ short8 as_s8(uint4 u) { return __builtin_bit_cast(short8, u); }

__device__ __forceinline__ void gpcm_store(float th, int q,
                                           const float* __restrict__ alpha_mean,
                                           const float* __restrict__ beta_base,
                                           const float* __restrict__ beta_gaps,
                                           float* __restrict__ out, size_t idx) {
    float a  = __expf(alpha_mean[q]);
    float b0 = beta_base[q];
    float2 g = *reinterpret_cast<const float2*>(&beta_gaps[q * (K_CAT - 2)]);
    float g0 = log1pf(__expf(g.x));
    float g1 = log1pf(__expf(g.y));
    float be1 = b0 + g0;
    float be2 = be1 + g1;
    float z0 = a * (th - b0);
    float z1 = a * (th - be1);
    float z2 = a * (th - be2);
    float c1 = z0, c2 = z0 + z1, c3 = z0 + z1 + z2;
    float cm = fmaxf(fmaxf(0.f, c1), fmaxf(c2, c3));
    float e0 = __expf(0.f - cm), e1 = __expf(c1 - cm), e2 = __expf(c2 - cm), e3 = __expf(c3 - cm);
    float si = __fdividef(1.0f, e0 + e1 + e2 + e3);
    float4 o4 = make_float4(e0 * si, e1 * si, e2 * si, e3 * si);
    *reinterpret_cast<float4*>(&out[idx * K_CAT]) = o4;
}

// Gather the lane's q-row slices (issue early to hide latency).
__device__ __forceinline__ void load_qf(const float* __restrict__ qrow, int h, float4 qf[8]) {
    #pragma unroll
    for (int s = 0; s < 4; ++s) {
        const float4* src = (const float4*)(qrow + s * 16 + h * 8);
        qf[2 * s]     = src[0];
        qf[2 * s + 1] = src[1];
    }
}

// 32x32x16 MFMA logits from preloaded qf: acc[mt][j] = logit for
// m = (j&3) + 8*((j>>2)&3) + 4*h + 32*mt, pair col p.
__device__ __forceinline__ void mfma_logits(
    const float4 qf[8], const unsigned short* __restrict__ ct,
    const float* __restrict__ bm, int h, int p, f32x16 acc[2])
{
    uint4 af[8];
    #pragma unroll
    for (int mt = 0; mt < 2; ++mt)
        #pragma unroll
        for (int s = 0; s < 4; ++s)
            af[mt * 4 + s] = *(const uint4*)(ct + (p + 32 * mt) * E_DIM + s * 16 + h * 8);
    #pragma unroll
    for (int mt = 0; mt < 2; ++mt)
        #pragma unroll
        for (int g = 0; g < 4; ++g) {
            float4 v = *(const float4*)(bm + 8 * g + 4 * h + 32 * mt);
            acc[mt][4 * g + 0] = v.x; acc[mt][4 * g + 1] = v.y;
            acc[mt][4 * g + 2] = v.z; acc[mt][4 * g + 3] = v.w;
        }
    #pragma unroll
    for (int s = 0; s < 4; ++s) {
        uint4 bf;
        bf.x = pk2rne(qf[2 * s].x,     qf[2 * s].y);
        bf.y = pk2rne(qf[2 * s].z,     qf[2 * s].w);
        bf.z = pk2rne(qf[2 * s + 1].x, qf[2 * s + 1].y);
        bf.w = pk2rne(qf[2 * s + 1].z, qf[2 * s + 1].w);
        short8 bfr = as_s8(bf);
        acc[0] = __builtin_amdgcn_mfma_f32_32x32x16_bf16(as_s8(af[s]),     bfr, acc[0], 0, 0, 0);
        acc[1] = __builtin_amdgcn_mfma_f32_32x32x16_bf16(as_s8(af[4 + s]), bfr, acc[1], 0, 0, 0);
    }
}

// Precompute Ct[m][e] bf16, bm, wbar, bbar, rm0, p0; zero wsum/emsum.
__global__ void k_pre(const float* __restrict__ q2k_w, const float* __restrict__ q2k_b,
                      const float* __restrict__ mkeys,
                      const float* __restrict__ ev_w, const float* __restrict__ ev_b,
                      const float* __restrict__ means, const float* __restrict__ logvars,
                      float* __restrict__ ws) {
    int gid = blockIdx.x * blockDim.x + threadIdx.x;
    if (gid < PRE_CT_END) {
        int e = gid >> 6, m = gid & 63;
        float s = 0.f;
        #pragma unroll
        for (int k = 0; k < KEY_DIM; ++k) s = fmaf(q2k_w[e * KEY_DIM + k], mkeys[m * KEY_DIM + k], s);
        ((unsigned short*)ws)[m * E_DIM + e] = bf16rne(s);   // transposed store
    } else if (gid < PRE_BM_END) {
        int m = gid - PRE_CT_END;
        float s = 0.f;
        #pragma unroll
        for (int k = 0; k < KEY_DIM; ++k) s = fmaf(q2k_b[k], mkeys[m * KEY_DIM + k], s);
        ws[OFF_BM + m] = s;
    } else if (gid < PRE_WBAR_END) {
        int e = gid - PRE_BM_END;
        float s = 0.f;
        for (int v = 0; v < V_DIM; ++v) s += ev_w[e * V_DIM + v];
        ws[OFF_WBAR + e] = s * (1.0f / V_DIM);
    } else if (gid == PRE_BBAR) {
        float s = 0.f;
        for (int v = 0; v < V_DIM; ++v) s += ev_b[v];
        ws[OFF_BBAR] = s * (1.0f / V_DIM);
    } else if (gid >= PRE_RM_BEG && gid < PRE_RM_END) {
        int m = gid - PRE_RM_BEG;
        const float4* mr = (const float4*)(means + (size_t)m * V_DIM);
        float s = 0.f;
        #pragma unroll
        for (int i = 0; i < V_DIM / 4; ++i) { float4 v = mr[i]; s += (v.x + v.y) + (v.z + v.w); }
        ws[OFF_RM0 + m] = s * (1.0f / V_DIM);
        ws[OFF_P0 + m]  = __expf(-logvars[(size_t)m * V_DIM]);  // row-uniform by construction
    } else if (gid >= PRE_Z_BEG && gid < PRE_Z_END) {
        ws[OFF_WSUM + (gid - PRE_Z_BEG)] = 0.f;
    }
}

// Stats-only attention: MFMA logits -> softmax -> fold -> atomics. No attn store.
// (256,4): 4 blocks/CU so all 800 blocks co-resident (no tail).
__global__ __launch_bounds__(256, 4) void k_attn(
    const float* __restrict__ qtab, const int* __restrict__ qs, const int* __restrict__ rs,
    const float* __restrict__ ws_ro,
    const float* __restrict__ qa_w, const float* __restrict__ qa_b,
    float* __restrict__ wsum, float* __restrict__ emsum,
    int B, float invNQ)
{
    __shared__ float4 lsEv[64];
    const int tid = threadIdx.x, wv = tid >> 6, lane = tid & 63;
    const int h = lane >> 5, p = lane & 31;
    const int t = blockIdx.x;
    const int b = blockIdx.y * 128 + wv * 32 + p;

    const int q = qs[(size_t)b * S_LEN + t];
    const int r = rs[(size_t)b * S_LEN + t];
    float4 qf[8];
    load_qf(qtab + (size_t)q * E_DIM, h, qf);   // issue gather early

    if (tid < 64) lsEv[tid] = make_float4(qa_w[tid], qa_w[E_DIM + tid], qa_b[tid],
                                          ws_ro[OFF_WBAR + tid]);
    const float bb = ws_ro[OFF_BBAR];

    f32x16 acc[2];
    mfma_logits(qf, (const unsigned short*)ws_ro, ws_ro + OFF_BM, h, p, acc);

    // softmax over 64 slots of pair p (half h holds 32)
    float av[32];
    float ssum = 0.f;
    #pragma unroll
    for (int j = 0; j < 16; ++j) { av[j]      = __expf(acc[0][j]); ssum += av[j]; }
    #pragma unroll
    for (int j = 0; j < 16; ++j) { av[16 + j] = __expf(acc[1][j]); ssum += av[16 + j]; }
    ssum += __shfl_xor(ssum, 32);
    const float inv = __fdividef(1.0f, ssum);

    // fold normalized attn over 32 pairs (within half); lane ends with j=lane&31
    #pragma unroll
    for (int j = 0; j < 32; ++j) av[j] *= inv;
    #pragma unroll
    for (int step = 0; step < 5; ++step) {
        const int sh = 1 << step;
        #pragma unroll
        for (int j = 0; j < (32 >> step) / 2; ++j) {
            float p0 = av[2 * j]     + __shfl_xor(av[2 * j], sh);
            float p1 = av[2 * j + 1] + __shfl_xor(av[2 * j + 1], sh);
            av[j] = (lane & sh) ? p1 : p0;
        }
    }
    {
        const int jj = lane & 31;
        const int m = (jj & 3) + 8 * ((jj >> 2) & 3) + 4 * h + 32 * (jj >> 4);
        atomicAdd(&wsum[t * M_SLOTS + m], av[0]);
    }

    __syncthreads();   // lsEv ready

    // evidence scalar
    float qn = (float)q * invNQ;
    float rn = (float)r * (1.0f / (K_CAT - 1));
    float evm = 0.f;
    #pragma unroll 8
    for (int e = 0; e < 32; ++e) {
        float4 pv = lsEv[h * 32 + e];
        float qa = fmaf(qn, pv.x, fmaf(rn, pv.y, pv.z));
        float ez = __expf(2.0f * qa);
        evm = fmaf(__fdividef(ez - 1.0f, ez + 1.0f), pv.w, evm);
    }
    evm += __shfl_xor(evm, 32);
    evm += bb;
    #pragma unroll
    for (int o = 16; o; o >>= 1) evm += __shfl_xor(evm, o);
    if (!lane) atomicAdd(&emsum[t], evm);
}

// Output: gather issued first, 4-wave associative prefix (hides gather), MFMA
// recompute, softmax, theta dot, GPCM. (256,4): no co-residency tail.
__global__ __launch_bounds__(256, 4) void k_out(
    const float* __restrict__ qtab, const int* __restrict__ qs,
    const float* __restrict__ ws_ro,
    const float* __restrict__ alpha_mean, const float* __restrict__ beta_base,
    const float* __restrict__ beta_gaps, float* __restrict__ out, int B, float invB)
{
    __shared__ float lsW[4][M_SLOTS], lsN[4][M_SLOTS];
    __shared__ float lsRmP[M_SLOTS];
    const int tid = threadIdx.x, wv = tid >> 6, lane = tid & 63;
    const int h = lane >> 5, p = lane & 31;
    const int t = blockIdx.x;
    const int b = blockIdx.y * 128 + wv * 32 + p;

    const int q = qs[(size_t)b * S_LEN + t];
    float4 qf[8];
    load_qf(qtab + (size_t)q * E_DIM, h, qf);   // issue gather BEFORE prefix

    // prefix partials: wave wv sums t-segment [s0,s1) over m=lane (associative),
    // 2-way unrolled for MLP.
    {
        const float* wsum  = ws_ro + OFF_WSUM;
        const float* emsum = ws_ro + OFF_EMSUM;
        const int seg = (t + 3) >> 2;
        const int s0 = wv * seg, s1 = min(s0 + seg, t);
        float pw0 = 0.f, pn0 = 0.f, pw1 = 0.f, pn1 = 0.f;
        int s = s0;
        for (; s + 2 <= s1; s += 2) {
            float w0 = wsum[s * M_SLOTS + lane];
            float w1 = wsum[(s + 1) * M_SLOTS + lane];
            float e0 = emsum[s], e1 = emsum[s + 1];
            pw0 += w0; pn0 = fmaf(e0, w0, pn0);
            pw1 += w1; pn1 = fmaf(e1, w1, pn1);
        }
        if (s < s1) {
            float w = wsum[s * M_SLOTS + lane];
            pw0 += w; pn0 = fmaf(emsum[s], w, pn0);
        }
        lsW[wv][lane] = pw0 + pw1; lsN[wv][lane] = pn0 + pn1;
    }
    __syncthreads();
    if (tid < 64) {
        const int m = tid;
        float sw = lsW[0][m] + lsW[1][m] + lsW[2][m] + lsW[3][m];
        float sn = lsN[0][m] + lsN[1][m] + lsN[2][m] + lsN[3][m];
        float den = ws_ro[OFF_P0 + m] + sw * invB;
        float num = fmaf(ws_ro[OFF_P0 + m], ws_ro[OFF_RM0 + m], sn * (invB * invB));
        // MFMA slot-permuted index: idx = h(m)*32 + mt(m)*16 + j(m)
        const int idx = ((m >> 2) & 1) * 32 + ((m >> 5) & 1) * 16 + (m & 3) + 4 * ((m >> 3) & 3);
        lsRmP[idx] = num / den;   // state BEFORE update at t
    }
    __syncthreads();

    f32x16 acc[2];
    mfma_logits(qf, (const unsigned short*)ws_ro, ws_ro + OFF_BM, h, p, acc);

    float ssum = 0.f, th = 0.f;
    const float* rmh = lsRmP + h * 32;
    #pragma unroll
    for (int j = 0; j < 16; ++j) {
        float e = __expf(acc[0][j]);
        ssum += e;
        th = fmaf(e, rmh[j], th);
    }
    #pragma unroll
    for (int j = 0; j < 16; ++j) {
        float e = __expf(acc[1][j]);
        ssum += e;
        th = fmaf(e, rmh[16 + j], th);
    }
    ssum += __shfl_xor(ssum, 32);
    th   += __shfl_xor(th, 32);
    th = __fdividef(th, ssum);

    if (!h) gpcm_store(th, q, alpha_mean, beta_base, beta_gaps, out, (size_t)b * S_LEN + t);
}

extern "C" void kernel_launch(void* const* d_in, const int* in_sizes, int n_in,
                              void* d_out, int out_size, void* d_ws, size_t ws_size,
                              hipStream_t stream) {
    const float* qtab       = (const float*)d_in[0];
    const float* alpha_mean = (const float*)d_in[1];
    const float* beta_base  = (const float*)d_in[2];
    const float* beta_gaps  = (const float*)d_in[3];
    const float* ab_means   = (const float*)d_in[4];
    const float* ab_logvars = (const float*)d_in[5];
    const float* mkeys      = (const float*)d_in[6];
    const float* q2k_w      = (const float*)d_in[7];
    const float* q2k_b      = (const float*)d_in[8];
    const float* qa_w       = (const float*)d_in[9];
    const float* qa_b       = (const float*)d_in[10];
    const float* ev_w       = (const float*)d_in[11];
    const float* ev_b       = (const float*)d_in[12];
    const int*   qs         = (const int*)d_in[13];
    const int*   rs         = (const int*)d_in[14];
    float* out = (float*)d_out;
    float* ws  = (float*)d_ws;

    const int NQ = in_sizes[1];
    const int S  = S_LEN;
    const int B  = in_sizes[13] / S;   // 512

    float* wsum  = ws + OFF_WSUM;
    float* emsum = ws + OFF_EMSUM;

    k_pre<<<(PRE_Z_END + 255) / 256, 256, 0, stream>>>(
        q2k_w, q2k_b, mkeys, ev_w, ev_b, ab_means, ab_logvars, ws);

    dim3 g(S, B / 128);
    k_attn<<<g, 256, 0, stream>>>(qtab, qs, rs, ws, qa_w, qa_b,
                                  wsum, emsum, B, 1.0f / (float)NQ);

    k_out<<<g, 256, 0, stream>>>(qtab, qs, ws, alpha_mean, beta_base,
                                 beta_gaps, out, B, 1.0f / (float)B);
}

// Round 14
// 47.159 us; speedup vs baseline: 1.3006x; 1.0013x over previous
//
#include <hip/hip_runtime.h>
#include <math.h>

// Problem constants (from reference)
#define M_SLOTS 64
#define E_DIM   64
#define KEY_DIM 64
#define V_DIM   128
#define K_CAT   4
#define S_LEN   200

typedef __attribute__((ext_vector_type(8)))  short short8;
typedef __attribute__((ext_vector_type(16))) float f32x16;

// ---------------- ws layout (float offsets) ----------------
#define OFF_CT     0                          // 4096 ushort = 2048 f  (Ct[m][e] bf16)
#define OFF_BM     2048                       // 64
#define OFF_WBAR   2112                       // 64
#define OFF_BBAR   2176                       // 1
#define OFF_RM0    2240                       // 64
#define OFF_P0     2304                       // 64
#define OFF_WSUM   2368                       // S*M = 12800 (zeroed by k_pre blocks 1..13)
#define OFF_EMSUM  (OFF_WSUM + S_LEN*M_SLOTS) // 200 (contiguous w/ wsum)
#define ZERO_CNT   (S_LEN*M_SLOTS + S_LEN)    // 13000 floats

// pack two f32 -> bf16 pair, round-to-nearest-even (for MFMA inputs)
__device__ __forceinline__ unsigned pk2rne(float lo, float hi) {
    unsigned ul = __float_as_uint(lo); ul += 0x7fffu + ((ul >> 16) & 1u);
    unsigned uh = __float_as_uint(hi); uh += 0x7fffu + ((uh >> 16) & 1u);
    return __builtin_amdgcn_perm(uh, ul, 0x07060302u);
}
__device__ __forceinline__ unsigned short bf16rne(float f) {
    unsigned u = __float_as_uint(f);
    return (unsigned short)((u + 0x7fffu + ((u >> 16) & 1u)) >> 16);
}
__device__ __forceinline__ short8 as_s8(uint4 u) { return __builtin_bit_cast(short8, u); }

__device__ __forceinline__ void gpcm_store(float th, int q,
                                           const float* __restrict__ alpha_mean,
                                           const float* __restrict__ beta_base,
                                           const float* __restrict__ beta_gaps,
                                           float* __restrict__ out, size_t idx) {
    float a  = __expf(alpha_mean[q]);
    float b0 = beta_base[q];
    float2 g = *reinterpret_cast<const float2*>(&beta_gaps[q * (K_CAT - 2)]);
    float g0 = log1pf(__expf(g.x));
    float g1 = log1pf(__expf(g.y));
    float be1 = b0 + g0;
    float be2 = be1 + g1;
    float z0 = a * (th - b0);
    float z1 = a * (th - be1);
    float z2 = a * (th - be2);
    float c1 = z0, c2 = z0 + z1, c3 = z0 + z1 + z2;
    float cm = fmaxf(fmaxf(0.f, c1), fmaxf(c2, c3));
    float e0 = __expf(0.f - cm), e1 = __expf(c1 - cm), e2 = __expf(c2 - cm), e3 = __expf(c3 - cm);
    float si = __fdividef(1.0f, e0 + e1 + e2 + e3);
    float4 o4 = make_float4(e0 * si, e1 * si, e2 * si, e3 * si);
    *reinterpret_cast<float4*>(&out[idx * K_CAT]) = o4;
}

// Gather the lane's q-row slices (issue early to hide latency).
__device__ __forceinline__ void load_qf(const float* __restrict__ qrow, int h, float4 qf[8]) {
    #pragma unroll
    for (int s = 0; s < 4; ++s) {
        const float4* src = (const float4*)(qrow + s * 16 + h * 8);
        qf[2 * s]     = src[0];
        qf[2 * s + 1] = src[1];
    }
}

// 32x32x16 MFMA logits from preloaded qf: acc[mt][j] = logit for
// m = (j&3) + 8*((j>>2)&3) + 4*h + 32*mt, pair col p.
__device__ __forceinline__ void mfma_logits(
    const float4 qf[8], const unsigned short* __restrict__ ct,
    const float* __restrict__ bm, int h, int p, f32x16 acc[2])
{
    uint4 af[8];
    #pragma unroll
    for (int mt = 0; mt < 2; ++mt)
        #pragma unroll
        for (int s = 0; s < 4; ++s)
            af[mt * 4 + s] = *(const uint4*)(ct + (p + 32 * mt) * E_DIM + s * 16 + h * 8);
    #pragma unroll
    for (int mt = 0; mt < 2; ++mt)
        #pragma unroll
        for (int g = 0; g < 4; ++g) {
            float4 v = *(const float4*)(bm + 8 * g + 4 * h + 32 * mt);
            acc[mt][4 * g + 0] = v.x; acc[mt][4 * g + 1] = v.y;
            acc[mt][4 * g + 2] = v.z; acc[mt][4 * g + 3] = v.w;
        }
    #pragma unroll
    for (int s = 0; s < 4; ++s) {
        uint4 bf;
        bf.x = pk2rne(qf[2 * s].x,     qf[2 * s].y);
        bf.y = pk2rne(qf[2 * s].z,     qf[2 * s].w);
        bf.z = pk2rne(qf[2 * s + 1].x, qf[2 * s + 1].y);
        bf.w = pk2rne(qf[2 * s + 1].z, qf[2 * s + 1].w);
        short8 bfr = as_s8(bf);
        acc[0] = __builtin_amdgcn_mfma_f32_32x32x16_bf16(as_s8(af[s]),     bfr, acc[0], 0, 0, 0);
        acc[1] = __builtin_amdgcn_mfma_f32_32x32x16_bf16(as_s8(af[4 + s]), bfr, acc[1], 0, 0, 0);
    }
}

// k_pre v2: 14 blocks. Block 0: 4 waves, each one 32x32 Ct tile via MFMA
// (D[m][e] = sum_k mkeys[m,k]*q2k_w[e,k], r12-verified layout) + per-wave
// side duties. Blocks 1..13: zero wsum/emsum with float4 stores.
__global__ __launch_bounds__(256) void k_pre(
    const float* __restrict__ q2k_w, const float* __restrict__ q2k_b,
    const float* __restrict__ mkeys,
    const float* __restrict__ ev_w, const float* __restrict__ ev_b,
    const float* __restrict__ means, const float* __restrict__ logvars,
    float* __restrict__ ws)
{
    const int tid = threadIdx.x;
    if (blockIdx.x != 0) {
        int i = ((int)blockIdx.x - 1) * 1024 + tid * 4;
        if (i + 4 <= ZERO_CNT) {
            *reinterpret_cast<float4*>(ws + OFF_WSUM + i) = make_float4(0.f, 0.f, 0.f, 0.f);
        } else {
            for (int j = i; j < ZERO_CNT; ++j) ws[OFF_WSUM + j] = 0.f;
        }
        return;
    }
    const int wv = tid >> 6, lane = tid & 63;
    const int h = lane >> 5, p = lane & 31;

    // Ct tile (m0, e0) via 4 MFMAs; store bf16 to global.
    {
        const int m0 = (wv & 1) * 32, e0 = (wv >> 1) * 32;
        f32x16 d;
        #pragma unroll
        for (int i = 0; i < 16; ++i) d[i] = 0.f;
        #pragma unroll
        for (int s = 0; s < 4; ++s) {
            const float* ar = mkeys + (m0 + p) * KEY_DIM + s * 16 + h * 8;
            const float* br = q2k_w + (e0 + p) * KEY_DIM + s * 16 + h * 8;
            float4 a0 = *(const float4*)ar, a1 = *(const float4*)(ar + 4);
            float4 b0 = *(const float4*)br, b1 = *(const float4*)(br + 4);
            uint4 au, bu;
            au.x = pk2rne(a0.x, a0.y); au.y = pk2rne(a0.z, a0.w);
            au.z = pk2rne(a1.x, a1.y); au.w = pk2rne(a1.z, a1.w);
            bu.x = pk2rne(b0.x, b0.y); bu.y = pk2rne(b0.z, b0.w);
            bu.z = pk2rne(b1.x, b1.y); bu.w = pk2rne(b1.z, b1.w);
            d = __builtin_amdgcn_mfma_f32_32x32x16_bf16(as_s8(au), as_s8(bu), d, 0, 0, 0);
        }
        unsigned short* ct = (unsigned short*)ws;
        #pragma unroll
        for (int j = 0; j < 16; ++j) {
            int row = (j & 3) + 8 * ((j >> 2) & 3) + 4 * h;
            ct[(m0 + row) * E_DIM + e0 + p] = bf16rne(d[j]);
        }
    }

    if (wv == 0) {          // wbar[e] = rowmean(ev_w[e]); for e = lane
        float s = 0.f;
        const float4* er = (const float4*)(ev_w + (size_t)lane * V_DIM);
        #pragma unroll
        for (int i = 0; i < V_DIM / 4; ++i) {
            float4 v = er[i];
            s += (v.x + v.y) + (v.z + v.w);
        }
        ws[OFF_WBAR + lane] = s * (1.0f / V_DIM);
    } else if (wv == 1) {   // bm[m] = q2k_b . mkeys[m]; bbar
        float s = 0.f;
        const float4* mk = (const float4*)(mkeys + lane * KEY_DIM);
        const float4* qb = (const float4*)q2k_b;
        #pragma unroll
        for (int i = 0; i < KEY_DIM / 4; ++i) {
            float4 a = mk[i], c = qb[i];
            s += a.x * c.x + a.y * c.y + a.z * c.z + a.w * c.w;
        }
        ws[OFF_BM + lane] = s;
        float bbv = ev_b[lane] + ev_b[64 + lane];
        #pragma unroll
        for (int o = 32; o; o >>= 1) bbv += __shfl_xor(bbv, o);
        if (!lane) ws[OFF_BBAR] = bbv * (1.0f / V_DIM);
    } else if (wv == 2) {   // rm0/p0
        float s = 0.f;
        const float4* mr = (const float4*)(means + (size_t)lane * V_DIM);
        #pragma unroll
        for (int i = 0; i < V_DIM / 4; ++i) {
            float4 v = mr[i];
            s += (v.x + v.y) + (v.z + v.w);
        }
        ws[OFF_RM0 + lane] = s * (1.0f / V_DIM);
        ws[OFF_P0 + lane]  = __expf(-logvars[(size_t)lane * V_DIM]);  // row-uniform
    }
}

// Stats-only attention: MFMA logits -> softmax -> fold -> atomics. No attn store.
// (256,4): all 800 blocks co-resident.
__global__ __launch_bounds__(256, 4) void k_attn(
    const float* __restrict__ qtab, const int* __restrict__ qs, const int* __restrict__ rs,
    const float* __restrict__ ws_ro,
    const float* __restrict__ qa_w, const float* __restrict__ qa_b,
    float* __restrict__ wsum, float* __restrict__ emsum,
    int B, float invNQ)
{
    __shared__ float4 lsEv[64];
    const int tid = threadIdx.x, wv = tid >> 6, lane = tid & 63;
    const int h = lane >> 5, p = lane & 31;
    const int t = blockIdx.x;
    const int b = blockIdx.y * 128 + wv * 32 + p;

    const int q = qs[(size_t)b * S_LEN + t];
    const int r = rs[(size_t)b * S_LEN + t];
    float4 qf[8];
    load_qf(qtab + (size_t)q * E_DIM, h, qf);   // issue gather early

    if (tid < 64) lsEv[tid] = make_float4(qa_w[tid], qa_w[E_DIM + tid], qa_b[tid],
                                          ws_ro[OFF_WBAR + tid]);
    const float bb = ws_ro[OFF_BBAR];

    f32x16 acc[2];
    mfma_logits(qf, (const unsigned short*)ws_ro, ws_ro + OFF_BM, h, p, acc);

    // softmax over 64 slots of pair p (half h holds 32)
    float av[32];
    float ssum = 0.f;
    #pragma unroll
    for (int j = 0; j < 16; ++j) { av[j]      = __expf(acc[0][j]); ssum += av[j]; }
    #pragma unroll
    for (int j = 0; j < 16; ++j) { av[16 + j] = __expf(acc[1][j]); ssum += av[16 + j]; }
    ssum += __shfl_xor(ssum, 32);
    const float inv = __fdividef(1.0f, ssum);

    // fold normalized attn over 32 pairs (within half); lane ends with j=lane&31
    #pragma unroll
    for (int j = 0; j < 32; ++j) av[j] *= inv;
    #pragma unroll
    for (int step = 0; step < 5; ++step) {
        const int sh = 1 << step;
        #pragma unroll
        for (int j = 0; j < (32 >> step) / 2; ++j) {
            float p0 = av[2 * j]     + __shfl_xor(av[2 * j], sh);
            float p1 = av[2 * j + 1] + __shfl_xor(av[2 * j + 1], sh);
            av[j] = (lane & sh) ? p1 : p0;
        }
    }
    {
        const int jj = lane & 31;
        const int m = (jj & 3) + 8 * ((jj >> 2) & 3) + 4 * h + 32 * (jj >> 4);
        atomicAdd(&wsum[t * M_SLOTS + m], av[0]);
    }

    __syncthreads();   // lsEv ready

    // evidence scalar
    float qn = (float)q * invNQ;
    float rn = (float)r * (1.0f / (K_CAT - 1));
    float evm = 0.f;
    #pragma unroll 8
    for (int e = 0; e < 32; ++e) {
        float4 pv = lsEv[h * 32 + e];
        float qa = fmaf(qn, pv.x, fmaf(rn, pv.y, pv.z));
        float ez = __expf(2.0f * qa);
        evm = fmaf(__fdividef(ez - 1.0f, ez + 1.0f), pv.w, evm);
    }
    evm += __shfl_xor(evm, 32);
    evm += bb;
    #pragma unroll
    for (int o = 16; o; o >>= 1) evm += __shfl_xor(evm, o);
    if (!lane) atomicAdd(&emsum[t], evm);
}

// Output: gather issued first, 4-wave associative prefix (hides gather), MFMA
// recompute, softmax, theta dot, GPCM.
__global__ __launch_bounds__(256, 4) void k_out(
    const float* __restrict__ qtab, const int* __restrict__ qs,
    const float* __restrict__ ws_ro,
    const float* __restrict__ alpha_mean, const float* __restrict__ beta_base,
    const float* __restrict__ beta_gaps, float* __restrict__ out, int B, float invB)
{
    __shared__ float lsW[4][M_SLOTS], lsN[4][M_SLOTS];
    __shared__ float lsRmP[M_SLOTS];
    const int tid = threadIdx.x, wv = tid >> 6, lane = tid & 63;
    const int h = lane >> 5, p = lane & 31;
    const int t = blockIdx.x;
    const int b = blockIdx.y * 128 + wv * 32 + p;

    const int q = qs[(size_t)b * S_LEN + t];
    float4 qf[8];
    load_qf(qtab + (size_t)q * E_DIM, h, qf);   // issue gather BEFORE prefix

    // prefix partials: wave wv sums t-segment [s0,s1) over m=lane, 2-way unrolled
    {
        const float* wsum  = ws_ro + OFF_WSUM;
        const float* emsum = ws_ro + OFF_EMSUM;
        const int seg = (t + 3) >> 2;
        const int s0 = wv * seg, s1 = min(s0 + seg, t);
        float pw0 = 0.f, pn0 = 0.f, pw1 = 0.f, pn1 = 0.f;
        int s = s0;
        for (; s + 2 <= s1; s += 2) {
            float w0 = wsum[s * M_SLOTS + lane];
            float w1 = wsum[(s + 1) * M_SLOTS + lane];
            float e0 = emsum[s], e1 = emsum[s + 1];
            pw0 += w0; pn0 = fmaf(e0, w0, pn0);
            pw1 += w1; pn1 = fmaf(e1, w1, pn1);
        }
        if (s < s1) {
            float w = wsum[s * M_SLOTS + lane];
            pw0 += w; pn0 = fmaf(emsum[s], w, pn0);
        }
        lsW[wv][lane] = pw0 + pw1; lsN[wv][lane] = pn0 + pn1;
    }
    __syncthreads();
    if (tid < 64) {
        const int m = tid;
        float sw = lsW[0][m] + lsW[1][m] + lsW[2][m] + lsW[3][m];
        float sn = lsN[0][m] + lsN[1][m] + lsN[2][m] + lsN[3][m];
        float den = ws_ro[OFF_P0 + m] + sw * invB;
        float num = fmaf(ws_ro[OFF_P0 + m], ws_ro[OFF_RM0 + m], sn * (invB * invB));
        // MFMA slot-permuted index: idx = h(m)*32 + mt(m)*16 + j(m)
        const int idx = ((m >> 2) & 1) * 32 + ((m >> 5) & 1) * 16 + (m & 3) + 4 * ((m >> 3) & 3);
        lsRmP[idx] = num / den;   // state BEFORE update at t
    }
    __syncthreads();

    f32x16 acc[2];
    mfma_logits(qf, (const unsigned short*)ws_ro, ws_ro + OFF_BM, h, p, acc);

    float ssum = 0.f, th = 0.f;
    const float* rmh = lsRmP + h * 32;
    #pragma unroll
    for (int j = 0; j < 16; ++j) {
        float e = __expf(acc[0][j]);
        ssum += e;
        th = fmaf(e, rmh[j], th);
    }
    #pragma unroll
    for (int j = 0; j < 16; ++j) {
        float e = __expf(acc[1][j]);
        ssum += e;
        th = fmaf(e, rmh[16 + j], th);
    }
    ssum += __shfl_xor(ssum, 32);
    th   += __shfl_xor(th, 32);
    th = __fdividef(th, ssum);

    if (!h) gpcm_store(th, q, alpha_mean, beta_base, beta_gaps, out, (size_t)b * S_LEN + t);
}

extern "C" void kernel_launch(void* const* d_in, const int* in_sizes, int n_in,
                              void* d_out, int out_size, void* d_ws, size_t ws_size,
                              hipStream_t stream) {
    const float* qtab       = (const float*)d_in[0];
    const float* alpha_mean = (const float*)d_in[1];
    const float* beta_base  = (const float*)d_in[2];
    const float* beta_gaps  = (const float*)d_in[3];
    const float* ab_means   = (const float*)d_in[4];
    const float* ab_logvars = (const float*)d_in[5];
    const float* mkeys      = (const float*)d_in[6];
    const float* q2k_w      = (const float*)d_in[7];
    const float* q2k_b      = (const float*)d_in[8];
    const float* qa_w       = (const float*)d_in[9];
    const float* qa_b       = (const float*)d_in[10];
    const float* ev_w       = (const float*)d_in[11];
    const float* ev_b       = (const float*)d_in[12];
    const int*   qs         = (const int*)d_in[13];
    const int*   rs         = (const int*)d_in[14];
    float* out = (float*)d_out;
    float* ws  = (float*)d_ws;

    const int NQ = in_sizes[1];
    const int S  = S_LEN;
    const int B  = in_sizes[13] / S;   // 512

    float* wsum  = ws + OFF_WSUM;
    float* emsum = ws + OFF_EMSUM;

    k_pre<<<14, 256, 0, stream>>>(q2k_w, q2k_b, mkeys, ev_w, ev_b,
                                  ab_means, ab_logvars, ws);

    dim3 g(S, B / 128);
    k_attn<<<g, 256, 0, stream>>>(qtab, qs, rs, ws, qa_w, qa_b,
                                  wsum, emsum, B, 1.0f / (float)NQ);

    k_out<<<g, 256, 0, stream>>>(qtab, qs, ws, alpha_mean, beta_base,
                                 beta_gaps, out, B, 1.0f / (float)B);
}